// Round 1
// baseline (787.324 us; speedup 1.0000x reference)
//
#include <hip/hip_runtime.h>

// LIF layer: Wx = x @ W^T (x:[B,T,I] f32, W:[H,I] f32), then sequential scan
// over T:  u = al*(u - s) + (1-al)*wx ;  s = (u - 1 > 0) ? 1 : 0.
// fp32 end-to-end; accumulation order (sequential-k fma per (m,n)) is kept
// bitwise-identical to the verified R0/R1 kernel (absmax == 0.0).
//
// R2 changes:
//  * GEMM: B-fragment split 4+4 (conflict-free ds_read_b128), reg-prefetch +
//    LDS double-buffer with ONE barrier per tile. (Was LDS-pipe-bound: B reads
//    4-way bank-aliased; global latency exposed each tile.)
//  * Scan: producer/consumer. 4 loader waves stream 16KB chunks into a 4-deep
//    LDS ring via global_load_lds (counted vmcnt, loads in flight across
//    barriers); 1 compute wave scans out of LDS. Was 1.27 TB/s latency-bound.

#define ALPHA_LO_F ((float)0.8187307530779818)   // exp(-1/5)
#define ALPHA_HI_F ((float)0.9607894391523232)   // exp(-1/25)

typedef float v2f __attribute__((ext_vector_type(2)));

// ---------------------------------------------------------------------------
// Kernel 1: fp32 NT GEMM, 128x128 tile, BK=16, 256 threads, 8x8 acc/thread.
// ---------------------------------------------------------------------------
#define TM 128
#define TN 128
#define TK 16
__global__ __launch_bounds__(256) void gemm_nt_f32(
    const float* __restrict__ A,   // [M, K]
    const float* __restrict__ B,   // [N, K]
    float* __restrict__ C,         // [M, N]
    int M, int N, int K)
{
    __shared__ float As[2][TK][TM];
    __shared__ float Bs[2][TK][TN];

    const int tid = threadIdx.x;
    const int m0  = blockIdx.y * TM;
    const int n0  = blockIdx.x * TN;

    // staging map: row = tid>>1 (0..127), kq = (tid&1)*8
    const int lrow = tid >> 1;
    const int lkq  = (tid & 1) * 8;

    // compute map: 16x16 threads; rows tm*8..+7; cols {tn*4..+3} and {64+tn*4..+3}
    const int tm = tid >> 4;     // 0..15
    const int tn = tid & 15;     // 0..15

    v2f acc[8][4] = {};

    const float* Arow = A + (size_t)(m0 + lrow) * K + lkq;
    const float* Brow = B + (size_t)(n0 + lrow) * K + lkq;

    // ---- prologue: load + stage tile 0 into buffer 0
    float4 av0 = *(const float4*)(Arow);
    float4 av1 = *(const float4*)(Arow + 4);
    float4 bv0 = *(const float4*)(Brow);
    float4 bv1 = *(const float4*)(Brow + 4);
    {
        float va[8] = {av0.x, av0.y, av0.z, av0.w, av1.x, av1.y, av1.z, av1.w};
        float vb[8] = {bv0.x, bv0.y, bv0.z, bv0.w, bv1.x, bv1.y, bv1.z, bv1.w};
        #pragma unroll
        for (int j = 0; j < 8; ++j) {
            As[0][lkq + j][lrow] = va[j];
            Bs[0][lkq + j][lrow] = vb[j];
        }
    }
    __syncthreads();

    const int NT = K / TK;
    int cur = 0;
    for (int kt = 0; kt < NT; ++kt) {
        const bool pf = (kt + 1 < NT);
        if (pf) {
            // issue next tile's global loads early; latency hides under compute
            const float* An = Arow + (size_t)(kt + 1) * TK;
            const float* Bn = Brow + (size_t)(kt + 1) * TK;
            av0 = *(const float4*)(An);
            av1 = *(const float4*)(An + 4);
            bv0 = *(const float4*)(Bn);
            bv1 = *(const float4*)(Bn + 4);
        }

        #pragma unroll
        for (int k = 0; k < TK; ++k) {
            const float* Ak  = &As[cur][k][tm * 8];
            const float* Bk0 = &Bs[cur][k][tn * 4];        // conflict-free b128
            const float* Bk1 = &Bs[cur][k][64 + tn * 4];   // conflict-free b128
            float4 a0 = *(const float4*)(Ak);
            float4 a1 = *(const float4*)(Ak + 4);
            float4 b0 = *(const float4*)(Bk0);
            float4 b1 = *(const float4*)(Bk1);
            v2f bb[4];
            bb[0] = (v2f){b0.x, b0.y};  bb[1] = (v2f){b0.z, b0.w};
            bb[2] = (v2f){b1.x, b1.y};  bb[3] = (v2f){b1.z, b1.w};
            float a[8] = {a0.x, a0.y, a0.z, a0.w, a1.x, a1.y, a1.z, a1.w};
            #pragma unroll
            for (int i = 0; i < 8; ++i) {
                v2f ai = (v2f){a[i], a[i]};
                #pragma unroll
                for (int jv = 0; jv < 4; ++jv)
                    acc[i][jv] = __builtin_elementwise_fma(ai, bb[jv], acc[i][jv]);
            }
        }

        if (pf) {
            const int nb = cur ^ 1;
            float va[8] = {av0.x, av0.y, av0.z, av0.w, av1.x, av1.y, av1.z, av1.w};
            float vb[8] = {bv0.x, bv0.y, bv0.z, bv0.w, bv1.x, bv1.y, bv1.z, bv1.w};
            #pragma unroll
            for (int j = 0; j < 8; ++j) {
                As[nb][lkq + j][lrow] = va[j];
                Bs[nb][lkq + j][lrow] = vb[j];
            }
        }
        __syncthreads();   // one barrier per tile (double-buffered LDS)
        cur ^= 1;
    }

    #pragma unroll
    for (int i = 0; i < 8; ++i) {
        float* Crow = C + (size_t)(m0 + tm * 8 + i) * N + n0;
        float4 v0, v1;
        v0.x = acc[i][0].x; v0.y = acc[i][0].y; v0.z = acc[i][1].x; v0.w = acc[i][1].y;
        v1.x = acc[i][2].x; v1.y = acc[i][2].y; v1.z = acc[i][3].x; v1.w = acc[i][3].y;
        *(float4*)(Crow + tn * 4)      = v0;
        *(float4*)(Crow + 64 + tn * 4) = v1;
    }
}

// ---------------------------------------------------------------------------
// Kernel 2: LIF scan, producer/consumer.
// Block = 320 threads (5 waves) per (b, 64-h slab). Wave 0 computes the
// recurrence out of LDS; waves 1..4 stream Wx chunks (C_T=64 t-steps x 64 h
// = 16 KB) into a 4-deep LDS ring with global_load_lds dwordx4.
// Counted vmcnt(12) keeps 3 chunks (48 KB/block) in flight across barriers.
// LDS chunk layout matches global order (t-major, 256 B/t) -> linear dest.
// Compute reads lds[t][lane]: stride-1 across lanes = bank-conflict-free.
// ---------------------------------------------------------------------------
#define C_T  64
#define NBUF 4

__global__ __launch_bounds__(320) void lif_scan(
    float* __restrict__ buf,            // [B, T, H]: in = Wx, out = spikes
    const float* __restrict__ alpha,    // [H]
    const float* __restrict__ u0,       // [B, H]
    const float* __restrict__ s0,       // [B, H]
    int B, int T, int H)
{
    __shared__ float S[NBUF][C_T][64];  // 64 KB ring

    const int tid  = threadIdx.x;
    const int wid  = tid >> 6;
    const int lane = tid & 63;
    const int b    = blockIdx.y;
    const int h0   = blockIdx.x * 64;
    const int nch  = T / C_T;           // 16 for T=1024

    float* base = buf + (size_t)b * T * H + h0;

    if (wid == 0) {
        // ---- compute wave: lane = h within slab
        const int h = h0 + lane;
        float al = alpha[h];
        al = fminf(fmaxf(al, ALPHA_LO_F), ALPHA_HI_F);
        const float oma = 1.0f - al;
        float u = u0[(size_t)b * H + h];
        float s = s0[(size_t)b * H + h];

        for (int j = 0; j < nch; ++j) {
            asm volatile("s_barrier" ::: "memory");           // A: chunk j ready
            const float* Sj = &S[j & (NBUF - 1)][0][0] + lane;
            float* orow = base + (size_t)j * C_T * H + lane;
            for (int tb = 0; tb < C_T; tb += 16) {
                float w[16];
                #pragma unroll
                for (int tt = 0; tt < 16; ++tt)
                    w[tt] = Sj[(tb + tt) * 64];
                #pragma unroll
                for (int tt = 0; tt < 16; ++tt) {
                    u = al * (u - s) + oma * w[tt];           // same fp32 expr as R0/R1
                    s = (u - 1.0f > 0.0f) ? 1.0f : 0.0f;
                    w[tt] = s;
                }
                #pragma unroll
                for (int tt = 0; tt < 16; ++tt)
                    orow[(size_t)(tb + tt) * H] = w[tt];
            }
            // all LDS reads hard-complete before loaders may overwrite the buf
            asm volatile("s_waitcnt lgkmcnt(0)" ::: "memory");
            asm volatile("s_barrier" ::: "memory");           // B: buffer free
        }
    } else {
        // ---- loader waves: wave lw issues instrs i = lw + 4q, q=0..3 per chunk.
        // instr i covers LDS bytes [i*1024, i*1024+1024): t = i*4 + (lane>>4),
        // h = (lane&15)*4; dest = uniform base + lane*16 (linear, matches).
        const int lw = wid - 1;          // 0..3

        #define ISSUE_CHUNK(c)                                                  \
            {                                                                   \
                const int cc = (c);                                             \
                char* sb = (char*)&S[cc & (NBUF - 1)][0][0];                    \
                _Pragma("unroll")                                               \
                for (int q = 0; q < 4; ++q) {                                   \
                    const int i = lw + 4 * q;                                   \
                    const int t = cc * C_T + i * 4 + (lane >> 4);               \
                    const float* g = base + (size_t)t * H + (lane & 15) * 4;    \
                    __builtin_amdgcn_global_load_lds(                           \
                        (const __attribute__((address_space(1))) unsigned int*)g, \
                        (__attribute__((address_space(3))) unsigned int*)(sb + i * 1024), \
                        16, 0, 0);                                              \
                }                                                               \
            }

        // prologue: chunks 0..NBUF-2 (3 chunks, 48 KB in flight)
        for (int c = 0; c < NBUF - 1; ++c) ISSUE_CHUNK(c)

        for (int j = 0; j < nch; ++j) {
            const int c = j + NBUF - 1;
            if (c < nch) ISSUE_CHUNK(c)
            // wait: chunk j complete; allow chunks j+1..j+3 (4 instr each) in flight
            if (j < nch - 3)       asm volatile("s_waitcnt vmcnt(12)" ::: "memory");
            else if (j == nch - 3) asm volatile("s_waitcnt vmcnt(8)"  ::: "memory");
            else if (j == nch - 2) asm volatile("s_waitcnt vmcnt(4)"  ::: "memory");
            else                   asm volatile("s_waitcnt vmcnt(0)"  ::: "memory");
            asm volatile("s_barrier" ::: "memory");           // A: publish chunk j
            asm volatile("s_barrier" ::: "memory");           // B: compute done
        }
        #undef ISSUE_CHUNK
    }
}

extern "C" void kernel_launch(void* const* d_in, const int* in_sizes, int n_in,
                              void* d_out, int out_size, void* d_ws, size_t ws_size,
                              hipStream_t stream) {
    const float* x     = (const float*)d_in[0];   // [B, T, I]
    const float* W     = (const float*)d_in[1];   // [H, I]
    const float* alpha = (const float*)d_in[2];   // [H]
    const float* u0    = (const float*)d_in[3];   // [B, H]
    const float* s0    = (const float*)d_in[4];   // [B, H]
    float* out = (float*)d_out;                   // [B, T, H]

    const int H = in_sizes[2];
    const int I = in_sizes[1] / H;
    const int B = in_sizes[3] / H;
    const int T = in_sizes[0] / (B * I);
    const int M = B * T;

    // 1) Wx -> d_out (exactly [B,T,H] f32; reused in-place by the scan)
    dim3 grid1(H / TN, M / TM);
    gemm_nt_f32<<<grid1, 256, 0, stream>>>(x, W, out, M, H, I);

    // 2) scan over T, in-place, producer/consumer
    dim3 grid2(H / 64, B);
    lif_scan<<<grid2, 320, 0, stream>>>(out, alpha, u0, s0, B, T, H);
}

// Round 2
// 583.278 us; speedup vs baseline: 1.3498x; 1.3498x over previous
//
#include <hip/hip_runtime.h>

// LIF layer: Wx = x @ W^T (x:[B,T,I] f32, W:[H,I] f32), then sequential scan
// over T:  u = al*(u - s) + (1-al)*wx ;  s = (u - 1 > 0) ? 1 : 0.
// fp32 end-to-end; accumulation order (sequential-k fma per (m,n)) is kept
// bitwise-identical to the verified R0/R1 kernel (absmax == 0.0).
//
// R3: GEMM = R0 structure (single LDS buffer, 52 VGPR, ~3 blocks/CU) + the
// R2-verified conflict-free B-fragment split (4+4 cols per thread).
// R2 post-mortem: double-buffer + reg-prefetch blew VGPR 52->184, occupancy
// 36->12%, VALUBusy 72->53 (Guideline 6). The conflict fix itself was good:
// SQ_LDS_BANK_CONFLICT 4.19e7 -> 8.39e6. Keep the fix, drop the pipelining —
// resident-wave TLP (3 blocks/CU) already hides the staging latency (m99/m100).
// Scan: unchanged from R2 (producer/consumer, ~150 us).

#define ALPHA_LO_F ((float)0.8187307530779818)   // exp(-1/5)
#define ALPHA_HI_F ((float)0.9607894391523232)   // exp(-1/25)

typedef float v2f __attribute__((ext_vector_type(2)));

// ---------------------------------------------------------------------------
// Kernel 1: fp32 NT GEMM, 128x128 tile, BK=16, 256 threads, 8x8 acc/thread.
// LDS As[k][m], Bs[k][n]; staging scatter-writes are 2-way aliased (free,
// m136). A reads: 4 addresses 32B apart (8 banks) x16-lane broadcast = clean.
// B reads: 4+4 split -> 16 contiguous 16B chunks, worst 2-way at 128B wrap.
// ---------------------------------------------------------------------------
#define TM 128
#define TN 128
#define TK 16
__global__ __launch_bounds__(256) void gemm_nt_f32(
    const float* __restrict__ A,   // [M, K]
    const float* __restrict__ B,   // [N, K]
    float* __restrict__ C,         // [M, N]
    int M, int N, int K)
{
    __shared__ float As[TK][TM];
    __shared__ float Bs[TK][TN];

    const int tid = threadIdx.x;
    const int m0  = blockIdx.y * TM;
    const int n0  = blockIdx.x * TN;

    // staging map: row = tid>>1 (0..127), kq = (tid&1)*8; two float4 per tile
    const int lrow = tid >> 1;
    const int lkq  = (tid & 1) * 8;

    // compute map: 16x16 threads; rows tm*8..+7; cols {tn*4..+3} and {64+tn*4..+3}
    const int tm = tid >> 4;     // 0..15
    const int tn = tid & 15;     // 0..15

    v2f acc[8][4] = {};

    const float* Arow = A + (size_t)(m0 + lrow) * K + lkq;
    const float* Brow = B + (size_t)(n0 + lrow) * K + lkq;

    for (int k0 = 0; k0 < K; k0 += TK) {
        float4 av0 = *(const float4*)(Arow + k0);
        float4 av1 = *(const float4*)(Arow + k0 + 4);
        float4 bv0 = *(const float4*)(Brow + k0);
        float4 bv1 = *(const float4*)(Brow + k0 + 4);
        As[lkq + 0][lrow] = av0.x;  As[lkq + 1][lrow] = av0.y;
        As[lkq + 2][lrow] = av0.z;  As[lkq + 3][lrow] = av0.w;
        As[lkq + 4][lrow] = av1.x;  As[lkq + 5][lrow] = av1.y;
        As[lkq + 6][lrow] = av1.z;  As[lkq + 7][lrow] = av1.w;
        Bs[lkq + 0][lrow] = bv0.x;  Bs[lkq + 1][lrow] = bv0.y;
        Bs[lkq + 2][lrow] = bv0.z;  Bs[lkq + 3][lrow] = bv0.w;
        Bs[lkq + 4][lrow] = bv1.x;  Bs[lkq + 5][lrow] = bv1.y;
        Bs[lkq + 6][lrow] = bv1.z;  Bs[lkq + 7][lrow] = bv1.w;
        __syncthreads();

        #pragma unroll
        for (int k = 0; k < TK; ++k) {
            const float* Ak  = &As[k][tm * 8];
            const float* Bk0 = &Bs[k][tn * 4];        // conflict-free b128
            const float* Bk1 = &Bs[k][64 + tn * 4];   // conflict-free b128
            float4 a0 = *(const float4*)(Ak);
            float4 a1 = *(const float4*)(Ak + 4);
            float4 b0 = *(const float4*)(Bk0);
            float4 b1 = *(const float4*)(Bk1);
            v2f bb[4];
            bb[0] = (v2f){b0.x, b0.y};  bb[1] = (v2f){b0.z, b0.w};
            bb[2] = (v2f){b1.x, b1.y};  bb[3] = (v2f){b1.z, b1.w};
            float a[8] = {a0.x, a0.y, a0.z, a0.w, a1.x, a1.y, a1.z, a1.w};
            #pragma unroll
            for (int i = 0; i < 8; ++i) {
                v2f ai = (v2f){a[i], a[i]};
                #pragma unroll
                for (int jv = 0; jv < 4; ++jv)
                    acc[i][jv] = __builtin_elementwise_fma(ai, bb[jv], acc[i][jv]);
            }
        }
        __syncthreads();
    }

    #pragma unroll
    for (int i = 0; i < 8; ++i) {
        float* Crow = C + (size_t)(m0 + tm * 8 + i) * N + n0;
        float4 v0, v1;
        v0.x = acc[i][0].x; v0.y = acc[i][0].y; v0.z = acc[i][1].x; v0.w = acc[i][1].y;
        v1.x = acc[i][2].x; v1.y = acc[i][2].y; v1.z = acc[i][3].x; v1.w = acc[i][3].y;
        *(float4*)(Crow + tn * 4)      = v0;
        *(float4*)(Crow + 64 + tn * 4) = v1;
    }
}

// ---------------------------------------------------------------------------
// Kernel 2: LIF scan, producer/consumer (unchanged from R2).
// Block = 320 threads (5 waves) per (b, 64-h slab). Wave 0 computes the
// recurrence out of LDS; waves 1..4 stream Wx chunks (C_T=64 t-steps x 64 h
// = 16 KB) into a 4-deep LDS ring with global_load_lds dwordx4.
// Counted vmcnt(12) keeps 3 chunks (48 KB/block) in flight across barriers.
// ---------------------------------------------------------------------------
#define C_T  64
#define NBUF 4

__global__ __launch_bounds__(320) void lif_scan(
    float* __restrict__ buf,            // [B, T, H]: in = Wx, out = spikes
    const float* __restrict__ alpha,    // [H]
    const float* __restrict__ u0,       // [B, H]
    const float* __restrict__ s0,       // [B, H]
    int B, int T, int H)
{
    __shared__ float S[NBUF][C_T][64];  // 64 KB ring

    const int tid  = threadIdx.x;
    const int wid  = tid >> 6;
    const int lane = tid & 63;
    const int b    = blockIdx.y;
    const int h0   = blockIdx.x * 64;
    const int nch  = T / C_T;           // 16 for T=1024

    float* base = buf + (size_t)b * T * H + h0;

    if (wid == 0) {
        // ---- compute wave: lane = h within slab
        const int h = h0 + lane;
        float al = alpha[h];
        al = fminf(fmaxf(al, ALPHA_LO_F), ALPHA_HI_F);
        const float oma = 1.0f - al;
        float u = u0[(size_t)b * H + h];
        float s = s0[(size_t)b * H + h];

        for (int j = 0; j < nch; ++j) {
            asm volatile("s_barrier" ::: "memory");           // A: chunk j ready
            const float* Sj = &S[j & (NBUF - 1)][0][0] + lane;
            float* orow = base + (size_t)j * C_T * H + lane;
            for (int tb = 0; tb < C_T; tb += 16) {
                float w[16];
                #pragma unroll
                for (int tt = 0; tt < 16; ++tt)
                    w[tt] = Sj[(tb + tt) * 64];
                #pragma unroll
                for (int tt = 0; tt < 16; ++tt) {
                    u = al * (u - s) + oma * w[tt];           // same fp32 expr as R0/R1
                    s = (u - 1.0f > 0.0f) ? 1.0f : 0.0f;
                    w[tt] = s;
                }
                #pragma unroll
                for (int tt = 0; tt < 16; ++tt)
                    orow[(size_t)(tb + tt) * H] = w[tt];
            }
            // all LDS reads hard-complete before loaders may overwrite the buf
            asm volatile("s_waitcnt lgkmcnt(0)" ::: "memory");
            asm volatile("s_barrier" ::: "memory");           // B: buffer free
        }
    } else {
        // ---- loader waves: wave lw issues instrs i = lw + 4q, q=0..3 per chunk.
        // instr i covers LDS bytes [i*1024, i*1024+1024): t = i*4 + (lane>>4),
        // h = (lane&15)*4; dest = uniform base + lane*16 (linear, matches).
        const int lw = wid - 1;          // 0..3

        #define ISSUE_CHUNK(c)                                                  \
            {                                                                   \
                const int cc = (c);                                             \
                char* sb = (char*)&S[cc & (NBUF - 1)][0][0];                    \
                _Pragma("unroll")                                               \
                for (int q = 0; q < 4; ++q) {                                   \
                    const int i = lw + 4 * q;                                   \
                    const int t = cc * C_T + i * 4 + (lane >> 4);               \
                    const float* g = base + (size_t)t * H + (lane & 15) * 4;    \
                    __builtin_amdgcn_global_load_lds(                           \
                        (const __attribute__((address_space(1))) unsigned int*)g, \
                        (__attribute__((address_space(3))) unsigned int*)(sb + i * 1024), \
                        16, 0, 0);                                              \
                }                                                               \
            }

        // prologue: chunks 0..NBUF-2 (3 chunks, 48 KB in flight)
        for (int c = 0; c < NBUF - 1; ++c) ISSUE_CHUNK(c)

        for (int j = 0; j < nch; ++j) {
            const int c = j + NBUF - 1;
            if (c < nch) ISSUE_CHUNK(c)
            // wait: chunk j complete; allow chunks j+1..j+3 (4 instr each) in flight
            if (j < nch - 3)       asm volatile("s_waitcnt vmcnt(12)" ::: "memory");
            else if (j == nch - 3) asm volatile("s_waitcnt vmcnt(8)"  ::: "memory");
            else if (j == nch - 2) asm volatile("s_waitcnt vmcnt(4)"  ::: "memory");
            else                   asm volatile("s_waitcnt vmcnt(0)"  ::: "memory");
            asm volatile("s_barrier" ::: "memory");           // A: publish chunk j
            asm volatile("s_barrier" ::: "memory");           // B: compute done
        }
        #undef ISSUE_CHUNK
    }
}

extern "C" void kernel_launch(void* const* d_in, const int* in_sizes, int n_in,
                              void* d_out, int out_size, void* d_ws, size_t ws_size,
                              hipStream_t stream) {
    const float* x     = (const float*)d_in[0];   // [B, T, I]
    const float* W     = (const float*)d_in[1];   // [H, I]
    const float* alpha = (const float*)d_in[2];   // [H]
    const float* u0    = (const float*)d_in[3];   // [B, H]
    const float* s0    = (const float*)d_in[4];   // [B, H]
    float* out = (float*)d_out;                   // [B, T, H]

    const int H = in_sizes[2];
    const int I = in_sizes[1] / H;
    const int B = in_sizes[3] / H;
    const int T = in_sizes[0] / (B * I);
    const int M = B * T;

    // 1) Wx -> d_out (exactly [B,T,H] f32; reused in-place by the scan)
    dim3 grid1(H / TN, M / TM);
    gemm_nt_f32<<<grid1, 256, 0, stream>>>(x, W, out, M, H, I);

    // 2) scan over T, in-place, producer/consumer
    dim3 grid2(H / 64, B);
    lif_scan<<<grid2, 320, 0, stream>>>(out, alpha, u0, s0, B, T, H);
}